// Round 5
// baseline (361.783 us; speedup 1.0000x reference)
//
#include <hip/hip_runtime.h>
#include <math.h>

#define B_ 2
#define N_ 16384
#define D_ 512
#define C_ 4
#define K_ 8
#define ROWS (B_*N_)      // 32768 rows per side
#define ROWS2 (2*ROWS)    // 65536 rows both sides
#define EPS_ 1e-12f

typedef unsigned short u16;
typedef unsigned int u32;
using short8  = __attribute__((ext_vector_type(8))) short;
using float4v = __attribute__((ext_vector_type(4))) float;

__device__ __forceinline__ u16 f2bf(float f) {
    union { float f; u32 u; } v; v.f = f;
    u32 r = v.u + 0x7fffu + ((v.u >> 16) & 1u);
    return (u16)(r >> 16);
}
__device__ __forceinline__ u32 pack2(float a, float b) {
    return (u32)f2bf(a) | ((u32)f2bf(b) << 16);
}
__device__ __forceinline__ float bf2f(u16 h) {
    union { u32 u; float f; } v; v.u = ((u32)h) << 16;
    return v.f;
}
__device__ __forceinline__ float fsigmoid(float x) { return 1.0f / (1.0f + __expf(-x)); }
__device__ __forceinline__ float ftanh(float x)    { return 1.0f - 2.0f / (__expf(2.0f * x) + 1.0f); }

__device__ __forceinline__ void load_lds16(const u16* g, u16* l) {
    __builtin_amdgcn_global_load_lds(
        (const __attribute__((address_space(1))) u32*)g,
        (__attribute__((address_space(3))) u32*)l, 16, 0, 0);
}
// Stage 8 rows x 64 k (bf16) of a row-major tile (row stride 512 u16) into LDS,
// fully coalesced, XOR-swizzled. LDS addr(r,c)=r*64 + (c^(r&7))*8 (u16).
__device__ __forceinline__ void stage_rows8(const u16* gtile, u16* ldsTile, int g, int lane) {
    int rg = lane >> 3;
    int c  = (lane & 7) ^ rg;
    load_lds16(gtile + (size_t)(g * 8 + rg) * 512 + c * 8, ldsTile + g * 512);
}
#define AFRAG(lds, R, c) (*(const short8*)&(lds)[(R) * 64 + (((c) ^ ((R) & 7)) * 8)])
// Fragment-packed B: frag(nf, ks)[lane][e] = Bt[nf*16 + (lane&15)][ks*32 + (lane>>4)*8 + e]
#define BFRAG(Bf, nf, ks, lane) (*(const short8*)&(Bf)[((size_t)((nf) * 16 + (ks)) << 9) + ((lane) << 3)])

// counted-vmcnt barrier discipline (T4): stage issued 2 regions ago is drained,
// the just-issued stage (4 youngest VMEM ops) stays in flight across s_barrier.
#define WAITV4 asm volatile("s_waitcnt vmcnt(4)" ::: "memory")
#define WAITV0 asm volatile("s_waitcnt vmcnt(0)" ::: "memory")
#define BAR __builtin_amdgcn_s_barrier()

// ---------------- P0: weight prep (fragment-major packing) ----------------
__global__ __launch_bounds__(256) void prep_weights_kernel(
    const float* __restrict__ Wp, const float* __restrict__ Wv, const float* __restrict__ Wu,
    const float* __restrict__ bv, const float* __restrict__ bu, const float* __restrict__ desc,
    u16* __restrict__ WpF, u16* __restrict__ WvuF, float* __restrict__ bvu,
    u16* __restrict__ descF)
{
    int idx = blockIdx.x * 256 + threadIdx.x;   // 0 .. 262143
    // fragment decode: idx = ((nf*16 + ks)*64 + l)*8 + e
    int e = idx & 7, l = (idx >> 3) & 63, ks = (idx >> 9) & 15, nf = idx >> 13;
    int k = ks * 32 + ((l >> 4) << 3) + e;
    int n = (nf << 4) + (l & 15);
    WpF[idx] = f2bf(Wp[(size_t)k * 512 + n]);
    int half = nf & 1, h = (nf >> 1) * 16 + (l & 15);
    WvuF[idx] = f2bf(half ? Wu[(size_t)k * 256 + h] : Wv[(size_t)k * 256 + h]);
    if (idx < 512) {
        int tl = idx >> 4, pr = tl >> 1, hf = tl & 1, hh = pr * 16 + (idx & 15);
        bvu[idx] = hf ? bu[hh] : bv[hh];
    }
    if (idx < 16384) {
        int j = idx & 7, dl = (idx >> 3) & 63, g = (idx >> 9) & 1, kt = idx >> 10;
        descF[idx] = f2bf(desc[(size_t)(g * 16 + (dl & 15)) * 512 + kt * 32 + (dl >> 4) * 8 + j]);
    }
}

// ---------------- K0: per-row L2-normalize x and cast to bf16 (both sides) ---------
__global__ __launch_bounds__(256) void rownorm_cast_kernel(
    const float* __restrict__ x_s, const float* __restrict__ x_l, u16* __restrict__ xn)
{
    int wave = threadIdx.x >> 6, lane = threadIdx.x & 63;
    size_t row = (size_t)blockIdx.x * 4 + wave;
    const float* xr = (row < (size_t)ROWS) ? (x_s + row * D_)
                                           : (x_l + (row - ROWS) * D_);
    float4 a = *(const float4*)&xr[lane * 8];
    float4 b = *(const float4*)&xr[lane * 8 + 4];
    float s = a.x*a.x + a.y*a.y + a.z*a.z + a.w*a.w
            + b.x*b.x + b.y*b.y + b.z*b.z + b.w*b.w;
#pragma unroll
    for (int off = 32; off; off >>= 1) s += __shfl_xor(s, off, 64);
    float inv = 1.0f / fmaxf(sqrtf(s), EPS_);
    uint4 o;
    o.x = pack2(a.x * inv, a.y * inv);
    o.y = pack2(a.z * inv, a.w * inv);
    o.z = pack2(b.x * inv, b.y * inv);
    o.w = pack2(b.z * inv, b.w * inv);
    *(uint4*)&xn[row * D_ + lane * 8] = o;
}

// XCD-aware block decode: grid 2048 linear, 4 N-blocks of an M-tile share d%8 (one XCD).
__device__ __forceinline__ void decode_mn(int d, int& M0, int& N0) {
    int n = (d >> 3) & 3;
    int m = (d & 7) | ((d >> 5) << 3);
    M0 = m * 128; N0 = n * 128;
}

#define STAGEA(ptr, ttv) \
    { _Pragma("unroll") \
      for (int s_ = 0; s_ < 4; ++s_) \
          stage_rows8(Arow + (ttv) * 64, (ptr), wave * 4 + s_, lane); }

#define LOADB(dst, ttv) \
    { _Pragma("unroll") \
      for (int j_ = 0; j_ < 4; ++j_) { \
          dst[j_]     = BFRAG(Bf, nfb + j_, (ttv) * 2 + 0, lane); \
          dst[4 + j_] = BFRAG(Bf, nfb + j_, (ttv) * 2 + 1, lane); \
      } }

#define GCOMP(PC, BR) \
    { _Pragma("unroll") \
      for (int kt = 0; kt < 2; ++kt) { \
          short8 af[4]; \
          _Pragma("unroll") \
          for (int i_ = 0; i_ < 4; ++i_) \
              af[i_] = AFRAG(PC, wm * 64 + i_ * 16 + lr, kt * 4 + lq); \
          _Pragma("unroll") \
          for (int i_ = 0; i_ < 4; ++i_) \
              _Pragma("unroll") \
              for (int j_ = 0; j_ < 4; ++j_) \
                  acc[i_][j_] = __builtin_amdgcn_mfma_f32_16x16x32_bf16(BR[kt * 4 + j_], af[i_], acc[i_][j_], 0, 0, 0); \
      } }

// ---------------- K1: GEMM xpraw = xn @ WpF + bias (128x128, counted-vmcnt pipe) --
__global__ __launch_bounds__(256, 2) void gemm_bias_kernel(
    const u16* __restrict__ A, const u16* __restrict__ Bf,
    const float* __restrict__ bias, u16* __restrict__ C, float* __restrict__ sumsq)
{
    __shared__ u16 ldsA[3][128 * 64];
    int t = threadIdx.x, wave = t >> 6, lane = t & 63;
    int lr = lane & 15, lq = lane >> 4;
    int wm = wave >> 1, wn = wave & 1;
    int M0, N0; decode_mn(blockIdx.x, M0, N0);
    const u16* Arow = A + (size_t)M0 * 512;
    const int nfb = (N0 >> 4) + wn * 4;

    float4v acc[4][4];
#pragma unroll
    for (int i = 0; i < 4; ++i)
#pragma unroll
        for (int j = 0; j < 4; ++j)
#pragma unroll
            for (int r = 0; r < 4; ++r) acc[i][j][r] = 0.f;

    short8 bA[8], bB[8];
    u16 *p0 = &ldsA[0][0], *p1 = &ldsA[1][0], *p2 = &ldsA[2][0];

    STAGEA(p0, 0);
    LOADB(bA, 0);
    STAGEA(p1, 1);
    WAITV0; BAR;

    for (int t2 = 0; t2 < 3; ++t2) {
        int tt = t2 * 2;
        LOADB(bB, tt + 1);
        STAGEA(p2, tt + 2);
        GCOMP(p0, bA);
        WAITV4; BAR;
        LOADB(bA, tt + 2);
        STAGEA(p0, tt + 3);
        GCOMP(p1, bB);
        WAITV4; BAR;
        u16* q0 = p0; u16* q1 = p1; p0 = p2; p1 = q0; p2 = q1;
    }
    // tail: tt=6 (buf p0), tt=7 (buf p1)
    LOADB(bB, 7);
    GCOMP(p0, bA);
    WAITV0; BAR;
    GCOMP(p1, bB);

    float4 b4[4];
#pragma unroll
    for (int j = 0; j < 4; ++j)
        b4[j] = *(const float4*)&bias[N0 + wn * 64 + j * 16 + lq * 4];
#pragma unroll
    for (int i = 0; i < 4; ++i) {
        int m = M0 + wm * 64 + i * 16 + lr;
        u16* crow = C + (size_t)m * 512;
        float sq = 0.f;
#pragma unroll
        for (int j = 0; j < 4; ++j) {
            int nb = N0 + wn * 64 + j * 16 + lq * 4;
            float v0 = acc[i][j][0] + b4[j].x, v1 = acc[i][j][1] + b4[j].y;
            float v2 = acc[i][j][2] + b4[j].z, v3 = acc[i][j][3] + b4[j].w;
            u16 h0 = f2bf(v0), h1 = f2bf(v1), h2 = f2bf(v2), h3 = f2bf(v3);
            uint2 o;
            o.x = (u32)h0 | ((u32)h1 << 16);
            o.y = (u32)h2 | ((u32)h3 << 16);
            *(uint2*)&crow[nb] = o;
            float q0 = bf2f(h0), q1 = bf2f(h1), q2 = bf2f(h2), q3 = bf2f(h3);
            sq += q0*q0 + q1*q1 + q2*q2 + q3*q3;
        }
        sq += __shfl_xor(sq, 16, 64);
        sq += __shfl_xor(sq, 32, 64);
        if (lq == 0) atomicAdd(&sumsq[m], sq);
    }
}

#define LOADD(dst, ttv) \
    { _Pragma("unroll") \
      for (int kt_ = 0; kt_ < 2; ++kt_) \
          _Pragma("unroll") \
          for (int g_ = 0; g_ < 2; ++g_) \
              dst[kt_ * 2 + g_] = *(const short8*)&descF[((((ttv) * 2 + kt_) * 2 + g_) << 9) + (lane << 3)]; }

#define GCOMPC(PC, BR, DR) \
    { _Pragma("unroll") \
      for (int kt = 0; kt < 2; ++kt) { \
          if (doCls) { \
              _Pragma("unroll") \
              for (int h_ = 0; h_ < 2; ++h_) { \
                  short8 afc = AFRAG(PC, wave * 32 + h_ * 16 + lr, kt * 4 + lq); \
                  accS[h_][0] = __builtin_amdgcn_mfma_f32_16x16x32_bf16(afc, DR[kt * 2 + 0], accS[h_][0], 0, 0, 0); \
                  accS[h_][1] = __builtin_amdgcn_mfma_f32_16x16x32_bf16(afc, DR[kt * 2 + 1], accS[h_][1], 0, 0, 0); \
              } \
          } \
          short8 af[4]; \
          _Pragma("unroll") \
          for (int i_ = 0; i_ < 4; ++i_) \
              af[i_] = AFRAG(PC, wm * 64 + i_ * 16 + lr, kt * 4 + lq); \
          _Pragma("unroll") \
          for (int i_ = 0; i_ < 4; ++i_) \
              _Pragma("unroll") \
              for (int j_ = 0; j_ < 4; ++j_) \
                  acc[i_][j_] = __builtin_amdgcn_mfma_f32_16x16x32_bf16(BR[kt * 4 + j_], af[i_], acc[i_][j_], 0, 0, 0); \
      } }

// ---------------- K2: gate GEMM (128x128, counted-vmcnt pipe) + cls on n==0 ------
__global__ __launch_bounds__(256, 2) void gatecls_kernel(
    const u16* __restrict__ A, const u16* __restrict__ Bf,
    const u16* __restrict__ descF,
    const float* __restrict__ bvu, const float* __restrict__ w_attn,
    const float* __restrict__ sumsq, float* __restrict__ Araw4,
    float* __restrict__ out10)
{
    __shared__ u16 ldsA[3][128 * 64];
    int t = threadIdx.x, wave = t >> 6, lane = t & 63;
    int lr = lane & 15, lq = lane >> 4;
    int wm = wave >> 1, wn = wave & 1;
    int M0, N0; decode_mn(blockIdx.x, M0, N0);
    const int nblk = (N0 >> 7);
    const bool doCls = (nblk == 0);
    const u16* Arow = A + (size_t)M0 * 512;
    const int nfb = (N0 >> 4) + wn * 4;

    float4v acc[4][4];
    float4v accS[2][2];
#pragma unroll
    for (int i = 0; i < 4; ++i)
#pragma unroll
        for (int j = 0; j < 4; ++j)
#pragma unroll
            for (int r = 0; r < 4; ++r) acc[i][j][r] = 0.f;
#pragma unroll
    for (int h = 0; h < 2; ++h)
#pragma unroll
        for (int r = 0; r < 4; ++r) { accS[h][0][r] = 0.f; accS[h][1][r] = 0.f; }

    short8 bA[8], bB[8];
    short8 dA[4], dB[4];
    u16 *p0 = &ldsA[0][0], *p1 = &ldsA[1][0], *p2 = &ldsA[2][0];

    STAGEA(p0, 0);
    LOADB(bA, 0);
    if (doCls) LOADD(dA, 0);
    STAGEA(p1, 1);
    WAITV0; BAR;

    for (int t2 = 0; t2 < 3; ++t2) {
        int tt = t2 * 2;
        LOADB(bB, tt + 1);
        if (doCls) LOADD(dB, tt + 1);
        STAGEA(p2, tt + 2);
        GCOMPC(p0, bA, dA);
        WAITV4; BAR;
        LOADB(bA, tt + 2);
        if (doCls) LOADD(dA, tt + 2);
        STAGEA(p0, tt + 3);
        GCOMPC(p1, bB, dB);
        WAITV4; BAR;
        u16* q0 = p0; u16* q1 = p1; p0 = p2; p1 = q0; p2 = q1;
    }
    // tail: tt=6 (buf p0), tt=7 (buf p1)
    LOADB(bB, 7);
    if (doCls) LOADD(dB, 7);
    GCOMPC(p0, bA, dA);
    WAITV0; BAR;
    GCOMPC(p1, bB, dB);

    // --- class scores (only n==0 blocks; each wave owns rows wave*32..+31) ---
    if (doCls) {
        const float scale = 0.04419417382415922f;   // 512^-0.5
        int side = (M0 >= ROWS) ? 1 : 0;
        float* cls = out10 + (size_t)side * ((size_t)ROWS * 4);
#pragma unroll
        for (int h = 0; h < 2; ++h) {
#pragma unroll
            for (int r = 0; r < 4; ++r) {
                int grow = M0 + wave * 32 + h * 16 + lq * 4 + r;
                float iv = 1.0f / fmaxf(sqrtf(sumsq[grow]), EPS_);
                float sv0 = accS[h][0][r] * iv, sv1 = accS[h][1][r] * iv;
#pragma unroll
                for (int g = 0; g < 2; ++g) {
                    float s = g ? sv1 : sv0;
                    float ts = s * scale;
                    float mx = ts;
                    mx = fmaxf(mx, __shfl_xor(mx, 1, 64));
                    mx = fmaxf(mx, __shfl_xor(mx, 2, 64));
                    mx = fmaxf(mx, __shfl_xor(mx, 4, 64));
                    float e = __expf(ts - mx);
                    float num = e * s, den = e;
                    num += __shfl_xor(num, 1, 64); den += __shfl_xor(den, 1, 64);
                    num += __shfl_xor(num, 2, 64); den += __shfl_xor(den, 2, 64);
                    num += __shfl_xor(num, 4, 64); den += __shfl_xor(den, 4, 64);
                    if ((lr & 7) == 0) {
                        int c = g * 2 + ((lr >> 3) & 1);
                        cls[(size_t)(grow - side * ROWS) * 4 + c] = num / den;
                    }
                }
            }
        }
    }

    // --- gated-attention partial over this block's 128 cols ---
    int colbase = N0 + wn * 64;
    int hbase = colbase >> 1;
    float4 bv4[2], bu4[2], w4[2];
#pragma unroll
    for (int p = 0; p < 2; ++p) {
        int nv = colbase + p * 32 + lq * 4;
        bv4[p] = *(const float4*)&bvu[nv];
        bu4[p] = *(const float4*)&bvu[nv + 16];
        w4[p]  = *(const float4*)&w_attn[hbase + p * 16 + lq * 4];
    }
    float* redA = (float*)&ldsA[0][0];   // overlay [2][128] (buf0 last read at tt=6)
#pragma unroll
    for (int i = 0; i < 4; ++i) {
        int rloc = wm * 64 + i * 16 + lr;
        float iv = 1.0f / fmaxf(sqrtf(sumsq[M0 + rloc]), EPS_);
        float part = 0.f;
#pragma unroll
        for (int p = 0; p < 2; ++p) {
#pragma unroll
            for (int r = 0; r < 4; ++r) {
                float v = acc[i][2 * p][r] * iv + (&bv4[p].x)[r];
                float u = acc[i][2 * p + 1][r] * iv + (&bu4[p].x)[r];
                part += ftanh(v) * (&w4[p].x)[r] * fsigmoid(u);
            }
        }
        part += __shfl_xor(part, 16, 64);
        part += __shfl_xor(part, 32, 64);
        if (lq == 0) redA[wn * 128 + rloc] = part;
    }
    __syncthreads();
    if (t < 128)
        Araw4[(size_t)nblk * ROWS2 + M0 + t] = redA[t] + redA[128 + t];
}

// ---------------- K5a: slab-sum + per-block (max, expsum) partials ----------------
__global__ __launch_bounds__(256) void areduce_kernel(
    float* __restrict__ Araw4, float* __restrict__ part)
{
    __shared__ float red[256];
    int t = threadIdx.x, g = blockIdx.y;
    size_t i0 = (size_t)g * N_ + blockIdx.x * 512 + t * 2;
    float v0 = Araw4[i0]     + Araw4[i0 + ROWS2]     + Araw4[i0 + 2*ROWS2]     + Araw4[i0 + 3*ROWS2];
    float v1 = Araw4[i0 + 1] + Araw4[i0 + 1 + ROWS2] + Araw4[i0 + 1 + 2*ROWS2] + Araw4[i0 + 1 + 3*ROWS2];
    *(float2*)&Araw4[i0] = make_float2(v0, v1);
    red[t] = fmaxf(v0, v1); __syncthreads();
    for (int s = 128; s; s >>= 1) { if (t < s) red[t] = fmaxf(red[t], red[t + s]); __syncthreads(); }
    float m = red[0]; __syncthreads();
    red[t] = __expf(v0 - m) + __expf(v1 - m); __syncthreads();
    for (int s = 128; s; s >>= 1) { if (t < s) red[t] += red[t + s]; __syncthreads(); }
    if (t == 0) {
        int pi = g * 32 + blockIdx.x;
        part[pi * 2] = m;
        part[pi * 2 + 1] = red[0];
    }
}

// ---------------- K5b: combine 32 partials per group -> mg[g] ----------------
__global__ __launch_bounds__(128) void acombine_kernel(
    const float* __restrict__ part, float* __restrict__ mg)
{
    int t = threadIdx.x;              // 0..127, two waves
    int g = t >> 5, j = t & 31;
    float m = part[(g * 32 + j) * 2];
    float s = part[(g * 32 + j) * 2 + 1];
    float mm = m;
#pragma unroll
    for (int off = 1; off < 32; off <<= 1) mm = fmaxf(mm, __shfl_xor(mm, off, 64));
    float sc = s * __expf(m - mm);
#pragma unroll
    for (int off = 1; off < 32; off <<= 1) sc += __shfl_xor(sc, off, 64);
    if (j == 0) {
        mg[g * 2] = mm;
        mg[g * 2 + 1] = 1.0f / sc;
    }
}

// ---------------- K6: pooling with inline softmax normalize ----------------
__global__ __launch_bounds__(256) void pool_kernel(
    const float* __restrict__ Araw, const float* __restrict__ sumsq,
    const float* __restrict__ mg, const u16* __restrict__ xpraw,
    float* __restrict__ slideAll)
{
    __shared__ float lds[4][512];
    int t = threadIdx.x, wave = t >> 6, lane = t & 63;
    int g = blockIdx.y;
    float m = mg[g * 2], is = mg[g * 2 + 1];
    size_t row0 = (size_t)g * N_ + (size_t)blockIdx.x * 256 + wave;
    float a[8] = {};
    for (int r = 0; r < 64; ++r) {
        size_t row = row0 + r * 4;
        float iv = 1.0f / fmaxf(sqrtf(sumsq[row]), EPS_);
        float av = __expf(Araw[row] - m) * is * iv;
        uint4 pk = *(const uint4*)&xpraw[row * D_ + lane * 8];
        a[0] += av * bf2f((u16)pk.x); a[1] += av * bf2f((u16)(pk.x >> 16));
        a[2] += av * bf2f((u16)pk.y); a[3] += av * bf2f((u16)(pk.y >> 16));
        a[4] += av * bf2f((u16)pk.z); a[5] += av * bf2f((u16)(pk.z >> 16));
        a[6] += av * bf2f((u16)pk.w); a[7] += av * bf2f((u16)(pk.w >> 16));
    }
#pragma unroll
    for (int i = 0; i < 8; ++i) lds[wave][lane * 8 + i] = a[i];
    __syncthreads();
#pragma unroll
    for (int q = 0; q < 2; ++q) {
        int c = t * 2 + q;
        float s = lds[0][c] + lds[1][c] + lds[2][c] + lds[3][c];
        atomicAdd(&slideAll[(size_t)g * 512 + c], s);
    }
}

// ---------------- K7: finalize ----------------
__global__ __launch_bounds__(512) void finalize_kernel(
    const float* __restrict__ slide_s, const float* __restrict__ slide_l,
    const float* __restrict__ desc, float* __restrict__ out)
{
    __shared__ float txt[4][512];
    __shared__ float ssn[2][512];
    __shared__ float sln[2][512];
    __shared__ float red[512];
    __shared__ float lg[8];
    int t = threadIdx.x;

    auto reduceSum = [&](float v) -> float {
        red[t] = v; __syncthreads();
        for (int s = 256; s; s >>= 1) { if (t < s) red[t] += red[t + s]; __syncthreads(); }
        float r = red[0]; __syncthreads();
        return r;
    };

    for (int c = 0; c < 4; ++c) {
        float m = -1e30f;
        for (int k = 0; k < 8; ++k) m = fmaxf(m, desc[((size_t)c * 8 + k) * 512 + t]);
        float ss = reduceSum(m * m);
        txt[c][t] = m / fmaxf(sqrtf(ss), EPS_);
    }
    for (int b = 0; b < 2; ++b) {
        float v = slide_s[b * 512 + t];
        float ss = reduceSum(v * v);
        ssn[b][t] = v / fmaxf(sqrtf(ss), EPS_);
        v = slide_l[b * 512 + t];
        ss = reduceSum(v * v);
        sln[b][t] = v / fmaxf(sqrtf(ss), EPS_);
    }
    __syncthreads();
    for (int b = 0; b < 2; ++b)
        for (int c = 0; c < 4; ++c) {
            float v = ssn[b][t] * txt[c][t] + sln[b][t] * txt[c][t];
            float s = reduceSum(v);
            if (t == 0) lg[b * 4 + c] = s;
        }
    __syncthreads();
    if (t < 2) {
        int b = t;
        float m = -1e30f;
        for (int c = 0; c < 4; ++c) m = fmaxf(m, lg[b * 4 + c]);
        float e[4]; float den = 0.f;
        for (int c = 0; c < 4; ++c) { e[c] = expf(lg[b * 4 + c] - m); den += e[c]; }
        int am = 0; float bm = -1.f;
        for (int c = 0; c < 4; ++c) {
            float pcl = e[c] / den;
            out[b * 4 + c] = pcl;
            if (pcl > bm) { bm = pcl; am = c; }
        }
        out[8 + b] = (float)am;
    }
}

extern "C" void kernel_launch(void* const* d_in, const int* in_sizes, int n_in,
                              void* d_out, int out_size, void* d_ws, size_t ws_size,
                              hipStream_t stream) {
    const float* x_s    = (const float*)d_in[0];
    const float* x_l    = (const float*)d_in[2];
    const float* W_proj = (const float*)d_in[4];
    const float* b_proj = (const float*)d_in[5];
    const float* desc   = (const float*)d_in[6];
    const float* Wv     = (const float*)d_in[7];
    const float* bv     = (const float*)d_in[8];
    const float* Wu     = (const float*)d_in[9];
    const float* bu     = (const float*)d_in[10];
    const float* w_attn = (const float*)d_in[11];
    float* out = (float*)d_out;

    // workspace layout (bytes):
    //  0         : xn    bf16 [65536x512]  (67108864)
    //  67108864  : xpraw bf16 [65536x512]  (67108864)
    //  134217728 : WpF   bf16 frag-packed  (524288)
    //  134742016 : WvuF  bf16 frag-packed  (524288)
    //  135266304 : descF bf16 fragment     (32768)
    //  135299072 : bvu   f32 [512]         (2048)
    //  135301120 : sumsq f32 [65536]       (262144)   } zeroed together
    //  135563264 : slideAll f32 [4x512]    (8192)     }
    //  135571456 : Araw4 f32 [4x65536]     (1048576)
    //  136620032 : part  f32 [4x32x2]      (1024)
    //  136621056 : mg    f32 [4x2]         (32)
    char* w = (char*)d_ws;
    u16* xn        = (u16*)w;
    u16* xpraw     = (u16*)(w + 67108864);
    u16* WpF       = (u16*)(w + 134217728);
    u16* WvuF      = (u16*)(w + 134742016);
    u16* descF     = (u16*)(w + 135266304);
    float* bvu     = (float*)(w + 135299072);
    float* sumsq   = (float*)(w + 135301120);
    float* slideAll= (float*)(w + 135563264);
    float* Araw4   = (float*)(w + 135571456);
    float* part    = (float*)(w + 136620032);
    float* mg      = (float*)(w + 136621056);

    hipMemsetAsync(sumsq, 0, 262144 + 8192, stream);   // sumsq + slideAll
    prep_weights_kernel<<<1024, 256, 0, stream>>>(W_proj, Wv, Wu, bv, bu, desc,
                                                  WpF, WvuF, bvu, descF);

    rownorm_cast_kernel<<<ROWS2 / 4, 256, 0, stream>>>(x_s, x_l, xn);
    gemm_bias_kernel<<<2048, 256, 0, stream>>>(xn, WpF, b_proj, xpraw, sumsq);
    gatecls_kernel<<<2048, 256, 0, stream>>>(xpraw, WvuF, descF, bvu, w_attn,
                                             sumsq, Araw4, out + 10);
    areduce_kernel<<<dim3(32, 4), 256, 0, stream>>>(Araw4, part);
    acombine_kernel<<<1, 128, 0, stream>>>(part, mg);
    pool_kernel<<<dim3(64, 4), 256, 0, stream>>>(Araw4, sumsq, mg, xpraw, slideAll);
    finalize_kernel<<<1, 512, 0, stream>>>(slideAll, slideAll + 1024, desc, out);
}

// Round 6
// 322.388 us; speedup vs baseline: 1.1222x; 1.1222x over previous
//
#include <hip/hip_runtime.h>
#include <math.h>

#define B_ 2
#define N_ 16384
#define D_ 512
#define C_ 4
#define K_ 8
#define ROWS (B_*N_)      // 32768 rows per side
#define ROWS2 (2*ROWS)    // 65536 rows both sides
#define EPS_ 1e-12f

typedef unsigned short u16;
typedef unsigned int u32;
using short8  = __attribute__((ext_vector_type(8))) short;
using float4v = __attribute__((ext_vector_type(4))) float;

__device__ __forceinline__ u16 f2bf(float f) {
    union { float f; u32 u; } v; v.f = f;
    u32 r = v.u + 0x7fffu + ((v.u >> 16) & 1u);
    return (u16)(r >> 16);
}
__device__ __forceinline__ u32 pack2(float a, float b) {
    return (u32)f2bf(a) | ((u32)f2bf(b) << 16);
}
__device__ __forceinline__ float bf2f(u16 h) {
    union { u32 u; float f; } v; v.u = ((u32)h) << 16;
    return v.f;
}
__device__ __forceinline__ float fsigmoid(float x) { return 1.0f / (1.0f + __expf(-x)); }
__device__ __forceinline__ float ftanh(float x)    { return 1.0f - 2.0f / (__expf(2.0f * x) + 1.0f); }

__device__ __forceinline__ void load_lds16(const u16* g, u16* l) {
    __builtin_amdgcn_global_load_lds(
        (const __attribute__((address_space(1))) u32*)g,
        (__attribute__((address_space(3))) u32*)l, 16, 0, 0);
}
// Stage 8 rows x 64 k (bf16) of a row-major tile (row stride 512 u16) into LDS,
// fully coalesced, XOR-swizzled. LDS addr(r,c)=r*64 + (c^(r&7))*8 (u16).
__device__ __forceinline__ void stage_rows8(const u16* gtile, u16* ldsTile, int g, int lane) {
    int rg = lane >> 3;
    int c  = (lane & 7) ^ rg;
    load_lds16(gtile + (size_t)(g * 8 + rg) * 512 + c * 8, ldsTile + g * 512);
}
#define AFRAG(lds, R, c) (*(const short8*)&(lds)[(R) * 64 + (((c) ^ ((R) & 7)) * 8)])
// Fragment-packed B: frag(nf, ks)[lane][e] = Bt[nf*16 + (lane&15)][ks*32 + (lane>>4)*8 + e]
#define BFRAG(Bf, nf, ks, lane) (*(const short8*)&(Bf)[((size_t)((nf) * 16 + (ks)) << 9) + ((lane) << 3)])

// ---------------- P0: weight prep (fragment-major packing) ----------------
__global__ __launch_bounds__(256) void prep_weights_kernel(
    const float* __restrict__ Wp, const float* __restrict__ Wv, const float* __restrict__ Wu,
    const float* __restrict__ bv, const float* __restrict__ bu, const float* __restrict__ desc,
    u16* __restrict__ WpF, u16* __restrict__ WvuF, float* __restrict__ bvu,
    u16* __restrict__ descF)
{
    int idx = blockIdx.x * 256 + threadIdx.x;   // 0 .. 262143
    // fragment decode: idx = ((nf*16 + ks)*64 + l)*8 + e
    int e = idx & 7, l = (idx >> 3) & 63, ks = (idx >> 9) & 15, nf = idx >> 13;
    int k = ks * 32 + ((l >> 4) << 3) + e;
    int n = (nf << 4) + (l & 15);
    WpF[idx] = f2bf(Wp[(size_t)k * 512 + n]);
    int half = nf & 1, h = (nf >> 1) * 16 + (l & 15);
    WvuF[idx] = f2bf(half ? Wu[(size_t)k * 256 + h] : Wv[(size_t)k * 256 + h]);
    if (idx < 512) {
        int tl = idx >> 4, pr = tl >> 1, hf = tl & 1, hh = pr * 16 + (idx & 15);
        bvu[idx] = hf ? bu[hh] : bv[hh];
    }
    if (idx < 16384) {
        int j = idx & 7, dl = (idx >> 3) & 63, g = (idx >> 9) & 1, kt = idx >> 10;
        descF[idx] = f2bf(desc[(size_t)(g * 16 + (dl & 15)) * 512 + kt * 32 + (dl >> 4) * 8 + j]);
    }
}

// ---------------- K0: per-row L2-normalize x and cast to bf16 (both sides) ---------
__global__ __launch_bounds__(256) void rownorm_cast_kernel(
    const float* __restrict__ x_s, const float* __restrict__ x_l, u16* __restrict__ xn)
{
    int wave = threadIdx.x >> 6, lane = threadIdx.x & 63;
    size_t row = (size_t)blockIdx.x * 4 + wave;
    const float* xr = (row < (size_t)ROWS) ? (x_s + row * D_)
                                           : (x_l + (row - ROWS) * D_);
    float4 a = *(const float4*)&xr[lane * 8];
    float4 b = *(const float4*)&xr[lane * 8 + 4];
    float s = a.x*a.x + a.y*a.y + a.z*a.z + a.w*a.w
            + b.x*b.x + b.y*b.y + b.z*b.z + b.w*b.w;
#pragma unroll
    for (int off = 32; off; off >>= 1) s += __shfl_xor(s, off, 64);
    float inv = 1.0f / fmaxf(sqrtf(s), EPS_);
    uint4 o;
    o.x = pack2(a.x * inv, a.y * inv);
    o.y = pack2(a.z * inv, a.w * inv);
    o.z = pack2(b.x * inv, b.y * inv);
    o.w = pack2(b.z * inv, b.w * inv);
    *(uint4*)&xn[row * D_ + lane * 8] = o;
}

// ---------------- K1: FUSED proj-GEMM -> LDS tile -> gate-GEMM + cls + Gram -------
// One block owns 128 rows x full N=512 for BOTH GEMMs. Loop 2 reads its A-operand
// from the LDS tile written by loop 1's epilogue: zero barriers, zero staging.
__global__ __launch_bounds__(512, 2) void fused_kernel(
    const u16* __restrict__ A,          // xn
    const u16* __restrict__ BpF,        // W_proj frag-packed
    const u16* __restrict__ BvuF,       // Wv/Wu frag-packed interleaved
    const u16* __restrict__ descF,
    const float* __restrict__ bias,     // b_proj
    const float* __restrict__ bvu, const float* __restrict__ w_attn,
    u16* __restrict__ Cp,               // xpraw out (global, for pool)
    float* __restrict__ invn, float* __restrict__ Araw,
    float* __restrict__ out10)
{
    __shared__ u16 ldsStage[8192];      // 16 KB: loop-1 A staging (reused as f32 scratch)
    __shared__ u16 tile[65536];         // 128 KB: xpraw tile, 8 chunks of [128][64] swizzled
    int t = threadIdx.x, wave = t >> 6, lane = t & 63;
    int lr = lane & 15, lq = lane >> 4;
    int wm = wave >> 2, wn = wave & 3;  // wave covers rows wm*64..+64, cols wn*128..+128
    int M0 = blockIdx.x * 128;
    const u16* Arow = A + (size_t)M0 * 512;

    // ================= loop 1: xpraw = xn @ Wp + b =================
    float4v acc1[4][8];
#pragma unroll
    for (int i = 0; i < 4; ++i)
#pragma unroll
        for (int j = 0; j < 8; ++j)
#pragma unroll
            for (int r = 0; r < 4; ++r) acc1[i][j][r] = 0.f;

#pragma unroll 1
    for (int tt = 0; tt < 8; ++tt) {
#pragma unroll
        for (int s = 0; s < 2; ++s)
            stage_rows8(Arow + tt * 64, ldsStage, wave * 2 + s, lane);
        __syncthreads();
#pragma unroll
        for (int kt = 0; kt < 2; ++kt) {
            int ks = tt * 2 + kt;
            short8 af[4], bfr[8];
#pragma unroll
            for (int i = 0; i < 4; ++i)
                af[i] = AFRAG(ldsStage, wm * 64 + i * 16 + lr, kt * 4 + lq);
#pragma unroll
            for (int j = 0; j < 8; ++j)
                bfr[j] = BFRAG(BpF, wn * 8 + j, ks, lane);
#pragma unroll
            for (int i = 0; i < 4; ++i)
#pragma unroll
                for (int j = 0; j < 8; ++j)
                    acc1[i][j] = __builtin_amdgcn_mfma_f32_16x16x32_bf16(bfr[j], af[i], acc1[i][j], 0, 0, 0);
        }
        __syncthreads();
    }

    // ---- epilogue 1: +bias, bf16-round, write global xpraw AND the LDS tile ----
    {
        float4 b4[8];
#pragma unroll
        for (int j = 0; j < 8; ++j)
            b4[j] = *(const float4*)&bias[wn * 128 + j * 16 + lq * 4];
#pragma unroll
        for (int i = 0; i < 4; ++i) {
            int row = wm * 64 + i * 16 + lr;
            u16* crow = Cp + (size_t)(M0 + row) * 512;
#pragma unroll
            for (int j = 0; j < 8; ++j) {
                int col = wn * 128 + j * 16 + lq * 4;
                u16 h0 = f2bf(acc1[i][j][0] + b4[j].x);
                u16 h1 = f2bf(acc1[i][j][1] + b4[j].y);
                u16 h2 = f2bf(acc1[i][j][2] + b4[j].z);
                u16 h3 = f2bf(acc1[i][j][3] + b4[j].w);
                uint2 o;
                o.x = (u32)h0 | ((u32)h1 << 16);
                o.y = (u32)h2 | ((u32)h3 << 16);
                *(uint2*)&crow[col] = o;
                // LDS tile write in the SAME swizzled layout AFRAG expects:
                int kc = col >> 6, cc = col & 63;
                int c8 = cc >> 3, off8 = cc & 7;   // off8 in {0,4}
                *(uint2*)&tile[kc * 8192 + row * 64 + ((c8 ^ (row & 7)) * 8) + off8] = o;
            }
        }
    }
    __syncthreads();   // tile fully visible; loop 2 below is barrier-free

    // ================= loop 2: gate GEMM + cls + Gram, A from LDS =================
    float4v acc2[4][8];
    float4v accS[2], accG;
#pragma unroll
    for (int i = 0; i < 4; ++i)
#pragma unroll
        for (int j = 0; j < 8; ++j)
#pragma unroll
            for (int r = 0; r < 4; ++r) acc2[i][j][r] = 0.f;
#pragma unroll
    for (int r = 0; r < 4; ++r) { accS[0][r] = 0.f; accS[1][r] = 0.f; accG[r] = 0.f; }

#pragma unroll 1
    for (int tt = 0; tt < 8; ++tt) {
        const u16* tch = tile + tt * 8192;
#pragma unroll
        for (int kt = 0; kt < 2; ++kt) {
            int ks = tt * 2 + kt;
            // cls + Gram on this wave's 16 rows
            short8 afc = AFRAG(tch, wave * 16 + lr, kt * 4 + lq);
            short8 d0 = *(const short8*)&descF[((ks * 2 + 0) << 9) + (lane << 3)];
            short8 d1 = *(const short8*)&descF[((ks * 2 + 1) << 9) + (lane << 3)];
            accS[0] = __builtin_amdgcn_mfma_f32_16x16x32_bf16(afc, d0, accS[0], 0, 0, 0);
            accS[1] = __builtin_amdgcn_mfma_f32_16x16x32_bf16(afc, d1, accS[1], 0, 0, 0);
            accG    = __builtin_amdgcn_mfma_f32_16x16x32_bf16(afc, afc, accG, 0, 0, 0);
            // main gate GEMM
            short8 af[4], bfr[8];
#pragma unroll
            for (int i = 0; i < 4; ++i)
                af[i] = AFRAG(tch, wm * 64 + i * 16 + lr, kt * 4 + lq);
#pragma unroll
            for (int j = 0; j < 8; ++j)
                bfr[j] = BFRAG(BvuF, wn * 8 + j, ks, lane);
#pragma unroll
            for (int i = 0; i < 4; ++i)
#pragma unroll
                for (int j = 0; j < 8; ++j)
                    acc2[i][j] = __builtin_amdgcn_mfma_f32_16x16x32_bf16(bfr[j], af[i], acc2[i][j], 0, 0, 0);
        }
    }

    // ---- invn from Gram diagonal (each wave owns rows wave*16..+16) ----
    float* sInvF = (float*)ldsStage;            // [128]
    float* redA  = ((float*)ldsStage) + 128;    // [4][128]
#pragma unroll
    for (int r = 0; r < 4; ++r) {
        if (lr == lq * 4 + r) {
            float iv = 1.0f / fmaxf(sqrtf(accG[r]), EPS_);
            sInvF[wave * 16 + lq * 4 + r] = iv;
            invn[M0 + wave * 16 + lq * 4 + r] = iv;
        }
    }
    __syncthreads();

    // ---- class scores (R1-verified epilogue) ----
    {
        const float scale = 0.04419417382415922f;   // 512^-0.5
        int side = (M0 >= ROWS) ? 1 : 0;
        float* cls = out10 + (size_t)side * ((size_t)ROWS * 4);
        int rbase = M0 - side * ROWS + wave * 16;
#pragma unroll
        for (int r = 0; r < 4; ++r) {
            int rloc = rbase + lq * 4 + r;
            float iv = sInvF[wave * 16 + lq * 4 + r];
            float sv0 = accS[0][r] * iv, sv1 = accS[1][r] * iv;
#pragma unroll
            for (int g = 0; g < 2; ++g) {
                float s = g ? sv1 : sv0;
                float ts = s * scale;
                float mx = ts;
                mx = fmaxf(mx, __shfl_xor(mx, 1, 64));
                mx = fmaxf(mx, __shfl_xor(mx, 2, 64));
                mx = fmaxf(mx, __shfl_xor(mx, 4, 64));
                float e = __expf(ts - mx);
                float num = e * s, den = e;
                num += __shfl_xor(num, 1, 64); den += __shfl_xor(den, 1, 64);
                num += __shfl_xor(num, 2, 64); den += __shfl_xor(den, 2, 64);
                num += __shfl_xor(num, 4, 64); den += __shfl_xor(den, 4, 64);
                if ((lr & 7) == 0) {
                    int c = g * 2 + ((lr >> 3) & 1);
                    cls[(size_t)rloc * 4 + c] = num / den;
                }
            }
        }
    }

    // ---- gated-attention scalar: full row in block -> single Araw ----
    {
        int colbase = wn * 128;
        int hbase = wn * 64;
        float4 bv4[4], bu4[4], w4[4];
#pragma unroll
        for (int p = 0; p < 4; ++p) {
            int nv = colbase + p * 32 + lq * 4;
            bv4[p] = *(const float4*)&bvu[nv];
            bu4[p] = *(const float4*)&bvu[nv + 16];
            w4[p]  = *(const float4*)&w_attn[hbase + p * 16 + lq * 4];
        }
#pragma unroll
        for (int i = 0; i < 4; ++i) {
            int rloc = wm * 64 + i * 16 + lr;
            float iv = sInvF[rloc];
            float part = 0.f;
#pragma unroll
            for (int p = 0; p < 4; ++p) {
#pragma unroll
                for (int r = 0; r < 4; ++r) {
                    float v = acc2[i][2 * p][r] * iv + (&bv4[p].x)[r];
                    float u = acc2[i][2 * p + 1][r] * iv + (&bu4[p].x)[r];
                    part += ftanh(v) * (&w4[p].x)[r] * fsigmoid(u);
                }
            }
            part += __shfl_xor(part, 16, 64);
            part += __shfl_xor(part, 32, 64);
            if (lq == 0) redA[wn * 128 + rloc] = part;
        }
    }
    __syncthreads();
    if (t < 128)
        Araw[M0 + t] = redA[t] + redA[128 + t] + redA[256 + t] + redA[384 + t];
}

// ---------------- K5a: per-block (max, expsum) partials, single Araw ------------
__global__ __launch_bounds__(256) void areduce_kernel(
    const float* __restrict__ Araw, float* __restrict__ part)
{
    __shared__ float red[256];
    int t = threadIdx.x, g = blockIdx.y;
    size_t i0 = (size_t)g * N_ + blockIdx.x * 512 + t * 2;
    float2 v = *(const float2*)&Araw[i0];
    red[t] = fmaxf(v.x, v.y); __syncthreads();
    for (int s = 128; s; s >>= 1) { if (t < s) red[t] = fmaxf(red[t], red[t + s]); __syncthreads(); }
    float m = red[0]; __syncthreads();
    red[t] = __expf(v.x - m) + __expf(v.y - m); __syncthreads();
    for (int s = 128; s; s >>= 1) { if (t < s) red[t] += red[t + s]; __syncthreads(); }
    if (t == 0) {
        int pi = g * 32 + blockIdx.x;
        part[pi * 2] = m;
        part[pi * 2 + 1] = red[0];
    }
}

// ---------------- K5b: combine 32 partials per group -> mg[g] ----------------
__global__ __launch_bounds__(128) void acombine_kernel(
    const float* __restrict__ part, float* __restrict__ mg)
{
    int t = threadIdx.x;              // 0..127, two waves
    int g = t >> 5, j = t & 31;
    float m = part[(g * 32 + j) * 2];
    float s = part[(g * 32 + j) * 2 + 1];
    float mm = m;
#pragma unroll
    for (int off = 1; off < 32; off <<= 1) mm = fmaxf(mm, __shfl_xor(mm, off, 64));
    float sc = s * __expf(m - mm);
#pragma unroll
    for (int off = 1; off < 32; off <<= 1) sc += __shfl_xor(sc, off, 64);
    if (j == 0) {
        mg[g * 2] = mm;
        mg[g * 2 + 1] = 1.0f / sc;
    }
}

// ---------------- K6: pooling with inline softmax normalize ----------------
__global__ __launch_bounds__(256) void pool_kernel(
    const float* __restrict__ Araw, const float* __restrict__ invn,
    const float* __restrict__ mg, const u16* __restrict__ xpraw,
    float* __restrict__ slideAll)
{
    __shared__ float lds[4][512];
    int t = threadIdx.x, wave = t >> 6, lane = t & 63;
    int g = blockIdx.y;
    float m = mg[g * 2], is = mg[g * 2 + 1];
    size_t row0 = (size_t)g * N_ + (size_t)blockIdx.x * 256 + wave;
    float a[8] = {};
    for (int r = 0; r < 64; ++r) {
        size_t row = row0 + r * 4;
        float av = __expf(Araw[row] - m) * is * invn[row];
        uint4 pk = *(const uint4*)&xpraw[row * D_ + lane * 8];
        a[0] += av * bf2f((u16)pk.x); a[1] += av * bf2f((u16)(pk.x >> 16));
        a[2] += av * bf2f((u16)pk.y); a[3] += av * bf2f((u16)(pk.y >> 16));
        a[4] += av * bf2f((u16)pk.z); a[5] += av * bf2f((u16)(pk.z >> 16));
        a[6] += av * bf2f((u16)pk.w); a[7] += av * bf2f((u16)(pk.w >> 16));
    }
#pragma unroll
    for (int i = 0; i < 8; ++i) lds[wave][lane * 8 + i] = a[i];
    __syncthreads();
#pragma unroll
    for (int q = 0; q < 2; ++q) {
        int c = t * 2 + q;
        float s = lds[0][c] + lds[1][c] + lds[2][c] + lds[3][c];
        atomicAdd(&slideAll[(size_t)g * 512 + c], s);
    }
}

// ---------------- K7: finalize ----------------
__global__ __launch_bounds__(512) void finalize_kernel(
    const float* __restrict__ slide_s, const float* __restrict__ slide_l,
    const float* __restrict__ desc, float* __restrict__ out)
{
    __shared__ float txt[4][512];
    __shared__ float ssn[2][512];
    __shared__ float sln[2][512];
    __shared__ float red[512];
    __shared__ float lg[8];
    int t = threadIdx.x;

    auto reduceSum = [&](float v) -> float {
        red[t] = v; __syncthreads();
        for (int s = 256; s; s >>= 1) { if (t < s) red[t] += red[t + s]; __syncthreads(); }
        float r = red[0]; __syncthreads();
        return r;
    };

    for (int c = 0; c < 4; ++c) {
        float m = -1e30f;
        for (int k = 0; k < 8; ++k) m = fmaxf(m, desc[((size_t)c * 8 + k) * 512 + t]);
        float ss = reduceSum(m * m);
        txt[c][t] = m / fmaxf(sqrtf(ss), EPS_);
    }
    for (int b = 0; b < 2; ++b) {
        float v = slide_s[b * 512 + t];
        float ss = reduceSum(v * v);
        ssn[b][t] = v / fmaxf(sqrtf(ss), EPS_);
        v = slide_l[b * 512 + t];
        ss = reduceSum(v * v);
        sln[b][t] = v / fmaxf(sqrtf(ss), EPS_);
    }
    __syncthreads();
    for (int b = 0; b < 2; ++b)
        for (int c = 0; c < 4; ++c) {
            float v = ssn[b][t] * txt[c][t] + sln[b][t] * txt[c][t];
            float s = reduceSum(v);
            if (t == 0) lg[b * 4 + c] = s;
        }
    __syncthreads();
    if (t < 2) {
        int b = t;
        float m = -1e30f;
        for (int c = 0; c < 4; ++c) m = fmaxf(m, lg[b * 4 + c]);
        float e[4]; float den = 0.f;
        for (int c = 0; c < 4; ++c) { e[c] = expf(lg[b * 4 + c] - m); den += e[c]; }
        int am = 0; float bm = -1.f;
        for (int c = 0; c < 4; ++c) {
            float pcl = e[c] / den;
            out[b * 4 + c] = pcl;
            if (pcl > bm) { bm = pcl; am = c; }
        }
        out[8 + b] = (float)am;
    }
}

extern "C" void kernel_launch(void* const* d_in, const int* in_sizes, int n_in,
                              void* d_out, int out_size, void* d_ws, size_t ws_size,
                              hipStream_t stream) {
    const float* x_s    = (const float*)d_in[0];
    const float* x_l    = (const float*)d_in[2];
    const float* W_proj = (const float*)d_in[4];
    const float* b_proj = (const float*)d_in[5];
    const float* desc   = (const float*)d_in[6];
    const float* Wv     = (const float*)d_in[7];
    const float* bv     = (const float*)d_in[8];
    const float* Wu     = (const float*)d_in[9];
    const float* bu     = (const float*)d_in[10];
    const float* w_attn = (const float*)d_in[11];
    float* out = (float*)d_out;

    // workspace layout (bytes):
    //  0         : xn    bf16 [65536x512]  (67108864)
    //  67108864  : xpraw bf16 [65536x512]  (67108864)
    //  134217728 : WpF   bf16 frag-packed  (524288)
    //  134742016 : WvuF  bf16 frag-packed  (524288)
    //  135266304 : descF bf16 fragment     (32768)
    //  135299072 : bvu   f32 [512]         (2048)
    //  135301120 : invn  f32 [65536]       (262144)
    //  135563264 : Araw  f32 [65536]       (262144)
    //  135825408 : part  f32 [4x32x2]      (1024)
    //  135826432 : mg    f32 [4x2]         (32, padded to 1024)
    //  135827456 : slideAll f32 [4x512]    (8192)
    char* w = (char*)d_ws;
    u16* xn        = (u16*)w;
    u16* xpraw     = (u16*)(w + 67108864);
    u16* WpF       = (u16*)(w + 134217728);
    u16* WvuF      = (u16*)(w + 134742016);
    u16* descF     = (u16*)(w + 135266304);
    float* bvu     = (float*)(w + 135299072);
    float* invn    = (float*)(w + 135301120);
    float* Araw    = (float*)(w + 135563264);
    float* part    = (float*)(w + 135825408);
    float* mg      = (float*)(w + 135826432);
    float* slideAll= (float*)(w + 135827456);

    hipMemsetAsync(slideAll, 0, 8192, stream);
    prep_weights_kernel<<<1024, 256, 0, stream>>>(W_proj, Wv, Wu, bv, bu, desc,
                                                  WpF, WvuF, bvu, descF);

    rownorm_cast_kernel<<<ROWS2 / 4, 256, 0, stream>>>(x_s, x_l, xn);
    fused_kernel<<<512, 512, 0, stream>>>(xn, WpF, WvuF, descF, b_proj, bvu, w_attn,
                                          xpraw, invn, Araw, out + 10);
    areduce_kernel<<<dim3(32, 4), 256, 0, stream>>>(Araw, part);
    acombine_kernel<<<1, 128, 0, stream>>>(part, mg);
    pool_kernel<<<dim3(64, 4), 256, 0, stream>>>(Araw, invn, mg, xpraw, slideAll);
    finalize_kernel<<<1, 512, 0, stream>>>(slideAll, slideAll + 1024, desc, out);
}